// Round 3
// baseline (64483.258 us; speedup 1.0000x reference)
//
#include <hip/hip_runtime.h>

// Problem constants (shapes fixed by setup_inputs()).
#define B_ 1024
#define D_ 1024
#define F_ 32768
#define T_ 32
#define KSLOTS 32

// ---------- packed argmax key: (sortable float << 32) | (0xFFFFFFFF - idx) ----------
__device__ __forceinline__ unsigned int fkey(float f) {
    unsigned int u = __float_as_uint(f);
    return (u & 0x80000000u) ? ~u : (u | 0x80000000u);
}
__device__ __forceinline__ unsigned long long packkey(float v, unsigned int n) {
    return ((unsigned long long)fkey(v) << 32) | (unsigned long long)(0xFFFFFFFFu - n);
}

// ------------------- init: RT = X^T (residual starts at x), cnt = 0, amax = 0 -------------------
__global__ __launch_bounds__(256) void init_kernel(
    const float* __restrict__ X, float* __restrict__ RT,
    int* __restrict__ a_cnt, unsigned long long* __restrict__ amax)
{
    const int b = blockIdx.x, tid = threadIdx.x;
    for (int d = tid; d < D_; d += 256) RT[(size_t)d * B_ + b] = X[(size_t)b * D_ + d];
    if (tid == 0) { a_cnt[b] = 0; amax[b] = 0ull; }
}

// ------------------- fused SGEMM (ip = r @ xs^T) + per-row argmax -------------------
// A^T = RT [D_,B_] (residual transposed -> wave-uniform scalar loads via s_load),
// B = XS [F_,D_] row-major. Tile 128x128, BK=16, 256 threads = 4 waves.
// Wave w computes m-rows [w*32, w*32+32); each lane owns 2 n-cols -> acc[32][2].
// A comes through the SCALAR cache (v_fmac s-operand): per kk the only LDS traffic
// is one ds_read_b64/wave -> LDS pipe (R2 bottleneck, 63% VALUBusy cap) is relieved.
// Each C[m][n] remains a single ascending-k fmaf chain (numerics unchanged).
__global__ __launch_bounds__(256, 2) void gemm_argmax_kernel(
    const float* __restrict__ RT, const float* __restrict__ XS,
    unsigned long long* __restrict__ amax)
{
    __shared__ float Bs[16][132];   // [k][n], pad -> staging writes are <=2-way (free)

    const int tid = threadIdx.x;
    const int bn = blockIdx.x;          // 0..255 (N tiles) — x-fastest: same-XCD blocks
    const int bm = blockIdx.y;          // 0..7   (M tiles)   share XS slabs in L2
    const int m0 = bm * 128;
    const int n0 = bn * 128;

    const int wv   = __builtin_amdgcn_readfirstlane(tid >> 6);  // wave id (SGPR-uniform)
    const int lane = tid & 63;

    // B staging: 128 rows x 16 k per phase, 2 float4 per thread
    const int lrow = tid >> 2;
    const int lq   = tid & 3;
    const float* Bptr = XS + (size_t)(n0 + lrow) * D_ + lq * 4;

    // wave-uniform A base: A^T[k][m0 + wv*32 + j]
    const float* Abase = RT + m0 + wv * 32;

    float acc[32][2];
#pragma unroll
    for (int j = 0; j < 32; ++j) { acc[j][0] = 0.f; acc[j][1] = 0.f; }

    float4 b0 = *(const float4*)(Bptr);
    float4 b1 = *(const float4*)(Bptr + (size_t)64 * D_);

    for (int k0 = 0; k0 < D_; k0 += 16) {
        __syncthreads();   // previous compute done before overwriting LDS
        Bs[lq*4+0][lrow] = b0.x; Bs[lq*4+1][lrow] = b0.y;
        Bs[lq*4+2][lrow] = b0.z; Bs[lq*4+3][lrow] = b0.w;
        Bs[lq*4+0][64+lrow] = b1.x; Bs[lq*4+1][64+lrow] = b1.y;
        Bs[lq*4+2][64+lrow] = b1.z; Bs[lq*4+3][64+lrow] = b1.w;
        __syncthreads();
        if (k0 + 16 < D_) {   // prefetch next B tile during compute
            b0 = *(const float4*)(Bptr + k0 + 16);
            b1 = *(const float4*)(Bptr + (size_t)64 * D_ + k0 + 16);
        }
#pragma unroll
        for (int kk = 0; kk < 16; ++kk) {
            const float2 bv = *(const float2*)(&Bs[kk][lane * 2]);
            const float* Ak = Abase + (size_t)(k0 + kk) * B_;   // uniform -> s_load
#pragma unroll
            for (int j = 0; j < 32; ++j) {
                const float a = Ak[j];
                acc[j][0] = fmaf(a, bv.x, acc[j][0]);
                acc[j][1] = fmaf(a, bv.y, acc[j][1]);
            }
        }
    }

    // ---- argmax epilogue: in-lane best of 2 cols, butterfly across the wave ----
#pragma unroll
    for (int j = 0; j < 32; ++j) {
        unsigned long long ka = packkey(acc[j][0], (unsigned int)(n0 + lane * 2));
        unsigned long long kb = packkey(acc[j][1], (unsigned int)(n0 + lane * 2 + 1));
        unsigned long long best = (ka > kb) ? ka : kb;
        for (int off = 32; off > 0; off >>= 1) {
            unsigned long long o = __shfl_xor(best, off);
            best = (o > best) ? o : best;
        }
        if (lane == 0) atomicMax(&amax[m0 + wv * 32 + j], best);
    }
}

// ----------------- per-row sparse update: select, grad, step, relu, residual -----------------
__global__ __launch_bounds__(256) void update_kernel(
    const float* __restrict__ X, const float* __restrict__ XS,
    float* __restrict__ RT,
    int* __restrict__ a_idx, float* __restrict__ a_w, int* __restrict__ a_cnt,
    unsigned long long* __restrict__ amax)
{
    const int b = blockIdx.x;
    const int tid = threadIdx.x;
    __shared__ float s_r[D_];
    __shared__ int   s_idx[33];
    __shared__ float s_w[33];
    __shared__ float s_g[33];
    __shared__ int   s_cnt;
    __shared__ float s_red[8];

    for (int d = tid; d < D_; d += 256) s_r[d] = RT[(size_t)d * B_ + b];

    if (tid == 0) {
        int cnt = a_cnt[b];
        for (int j = 0; j < cnt; ++j) { s_idx[j] = a_idx[b*KSLOTS + j]; s_w[j] = a_w[b*KSLOTS + j]; }
        unsigned long long key = amax[b];
        int ni = (int)(0xFFFFFFFFu - (unsigned int)(key & 0xFFFFFFFFull));
        bool found = false;
        for (int j = 0; j < cnt; ++j) found = found || (s_idx[j] == ni);
        if (!found) {  // insert keeping indices ascending (matches numpy's sum-over-f order)
            int p = cnt;
            while (p > 0 && s_idx[p-1] > ni) { s_idx[p] = s_idx[p-1]; s_w[p] = s_w[p-1]; --p; }
            s_idx[p] = ni; s_w[p] = 0.f; ++cnt;
        }
        s_cnt = cnt;
    }
    __syncthreads();
    const int cnt = s_cnt;
    const int wave = tid >> 6, lane = tid & 63;

    // grad_j = <r, xs[idx_j]> (one wave per atom, round-robin)
    for (int j = wave; j < cnt; j += 4) {
        const float* xr = XS + (size_t)s_idx[j] * D_;
        float sum = 0.f;
#pragma unroll
        for (int i = 0; i < D_/64; ++i) { int d = lane + (i << 6); sum = fmaf(s_r[d], xr[d], sum); }
        for (int off = 32; off > 0; off >>= 1) sum += __shfl_down(sum, off);
        if (lane == 0) s_g[j] = sum;
    }
    __syncthreads();

    // c = grad @ xs (active atoms, ascending index); reduce c.c and c.r
    float cs = 0.f, cr = 0.f;
#pragma unroll
    for (int v = 0; v < 4; ++v) {
        const int d = tid + (v << 8);
        float cv = 0.f;
        for (int j = 0; j < cnt; ++j) cv = fmaf(s_g[j], XS[(size_t)s_idx[j]*D_ + d], cv);
        cs = fmaf(cv, cv, cs);
        cr = fmaf(cv, s_r[d], cr);
    }
    for (int off = 32; off > 0; off >>= 1) { cs += __shfl_down(cs, off); cr += __shfl_down(cr, off); }
    if (lane == 0) { s_red[wave] = cs; s_red[4 + wave] = cr; }
    __syncthreads();

    if (tid == 0) {
        const float cs_t = s_red[0] + s_red[1] + s_red[2] + s_red[3];
        const float cr_t = s_red[4] + s_red[5] + s_red[6] + s_red[7];
        const float ss = cr_t / fmaxf(cs_t, 1e-3f);
        int nc = 0;
        for (int j = 0; j < cnt; ++j) {           // weights = relu(w + ss*grad), drop zeros
            float nw = s_w[j] + ss * s_g[j];
            if (nw > 0.f) { s_idx[nc] = s_idx[j]; s_w[nc] = nw; ++nc; }
        }
        s_cnt = nc;
        a_cnt[b] = nc;
        for (int j = 0; j < nc; ++j) { a_idx[b*KSLOTS + j] = s_idx[j]; a_w[b*KSLOTS + j] = s_w[j]; }
        amax[b] = 0ull;                            // reset for next step's GEMM
    }
    __syncthreads();
    const int nc = s_cnt;

    // fresh residual written transposed: RT[d][b] = x[d] - sum_j w_j * xs[idx_j][d]
#pragma unroll
    for (int v = 0; v < 4; ++v) {
        const int d = tid + (v << 8);
        float s = 0.f;
        for (int j = 0; j < nc; ++j) s = fmaf(s_w[j], XS[(size_t)s_idx[j]*D_ + d], s);
        RT[(size_t)d * B_ + b] = X[(size_t)b*D_ + d] - s;
    }
}

// ----------------- finalize: top_k, decode x/y, losses, write outputs -----------------
__global__ __launch_bounds__(256) void finalize_kernel(
    const float* __restrict__ Y,
    const float* __restrict__ XS, const float* __restrict__ YS,
    const int* __restrict__ a_idx, const float* __restrict__ a_w, const int* __restrict__ a_cnt,
    float* __restrict__ out)
{
    const int b = blockIdx.x, tid = threadIdx.x;
    __shared__ int   s_idx[KSLOTS];
    __shared__ float s_w[KSLOTS];
    __shared__ int   o_idx[KSLOTS];
    __shared__ float o_w[KSLOTS];
    __shared__ float s_red[4];

    if (tid == 0) {
        int cnt = a_cnt[b];
        for (int j = 0; j < cnt; ++j) { s_idx[j] = a_idx[b*KSLOTS + j]; s_w[j] = a_w[b*KSLOTS + j]; }
        // insertion sort: desc weight, ties -> ascending index (lax.top_k semantics)
        for (int i = 1; i < cnt; ++i) {
            int ii = s_idx[i]; float ww = s_w[i];
            int p = i - 1;
            while (p >= 0 && (s_w[p] < ww || (s_w[p] == ww && s_idx[p] > ii))) {
                s_w[p+1] = s_w[p]; s_idx[p+1] = s_idx[p]; --p;
            }
            s_w[p+1] = ww; s_idx[p+1] = ii;
        }
        for (int j = 0; j < cnt; ++j) { o_idx[j] = s_idx[j]; o_w[j] = s_w[j]; }
        // pad remaining slots with the smallest indices whose weight is zero
        int p = cnt, f = 0;
        while (p < KSLOTS) {
            bool member = false;
            for (int j = 0; j < cnt; ++j) member = member || (s_idx[j] == f);
            if (!member) { o_idx[p] = f; o_w[p] = 0.f; ++p; }
            ++f;
        }
    }
    __syncthreads();

    if (tid < KSLOTS) {
        out[(size_t)b*KSLOTS + tid] = o_w[tid];
        out[32768 + (size_t)b*KSLOTS + tid] = (float)o_idx[tid];   // harness reads fp32
    }

    float lsum = 0.f;
    for (int d = tid; d < D_; d += 256) {
        float xr = 0.f, yr = 0.f;
#pragma unroll
        for (int k = 0; k < KSLOTS; ++k) {
            const size_t off = (size_t)o_idx[k] * D_ + d;
            xr = fmaf(o_w[k], XS[off], xr);
            yr = fmaf(o_w[k], YS[off], yr);
        }
        out[65536 + (size_t)b*D_ + d] = xr;
        out[65536 + 1048576 + (size_t)b*D_ + d] = yr;
        const float e = yr - Y[(size_t)b*D_ + d];
        lsum = fmaf(e, e, lsum);
    }
    const int wave = tid >> 6, lane = tid & 63;
    for (int off = 32; off > 0; off >>= 1) lsum += __shfl_down(lsum, off);
    if (lane == 0) s_red[wave] = lsum;
    __syncthreads();
    if (tid == 0) out[65536 + 2097152 + b] = s_red[0] + s_red[1] + s_red[2] + s_red[3];
}

extern "C" void kernel_launch(void* const* d_in, const int* in_sizes, int n_in,
                              void* d_out, int out_size, void* d_ws, size_t ws_size,
                              hipStream_t stream) {
    (void)in_sizes; (void)n_in; (void)out_size; (void)ws_size;
    const float* x  = (const float*)d_in[0];
    const float* y  = (const float*)d_in[1];
    const float* xs = (const float*)d_in[2];
    const float* ys = (const float*)d_in[3];
    // d_in[4] = target_l0 (hardcoded 32; shapes are fixed)
    float* out = (float*)d_out;

    // workspace layout (~4.3 MB)
    char* ws = (char*)d_ws;
    float*              RT    = (float*)(ws);                                   // 4 MB (residual^T)
    unsigned long long* amax  = (unsigned long long*)(ws + 4*1024*1024);        // 8 KB
    int*                a_cnt = (int*)(ws + 4*1024*1024 + 8192);                // 4 KB
    int*                a_idx = (int*)(ws + 4*1024*1024 + 8192 + 4096);         // 128 KB
    float*              a_w   = (float*)(ws + 4*1024*1024 + 8192 + 4096 + 131072); // 128 KB

    init_kernel<<<B_, 256, 0, stream>>>(x, RT, a_cnt, amax);

    dim3 ggrid(F_/128, B_/128);   // (256, 8): bn fastest -> XS slabs XCD-local in L2
    for (int t = 0; t < T_; ++t) {
        gemm_argmax_kernel<<<ggrid, 256, 0, stream>>>(RT, xs, amax);
        update_kernel<<<B_, 256, 0, stream>>>(x, xs, RT, a_idx, a_w, a_cnt, amax);
    }
    finalize_kernel<<<B_, 256, 0, stream>>>(y, xs, ys, a_idx, a_w, a_cnt, out);
}

// Round 4
// 34716.052 us; speedup vs baseline: 1.8574x; 1.8574x over previous
//
#include <hip/hip_runtime.h>

// Problem constants (shapes fixed by setup_inputs()).
#define B_ 1024
#define D_ 1024
#define F_ 32768
#define T_ 32
#define KSLOTS 32

// ---------- packed argmax key: (sortable float << 32) | (0xFFFFFFFF - idx) ----------
__device__ __forceinline__ unsigned int fkey(float f) {
    unsigned int u = __float_as_uint(f);
    return (u & 0x80000000u) ? ~u : (u | 0x80000000u);
}
__device__ __forceinline__ unsigned long long packkey(float v, unsigned int n) {
    return ((unsigned long long)fkey(v) << 32) | (unsigned long long)(0xFFFFFFFFu - n);
}

// ---------------------------- init: r = x, cnt = 0, amax = 0 ----------------------------
__global__ __launch_bounds__(256) void init_kernel(
    const float* __restrict__ X, float* __restrict__ Rres,
    int* __restrict__ a_cnt, unsigned long long* __restrict__ amax)
{
    const int b = blockIdx.x, tid = threadIdx.x;
    for (int d = tid; d < D_; d += 256) Rres[(size_t)b * D_ + d] = X[(size_t)b * D_ + d];
    if (tid == 0) { a_cnt[b] = 0; amax[b] = 0ull; }
}

// ------------------- fused SGEMM (ip = r @ xs^T) + per-row argmax -------------------
// A = Rres [B_,D_] row-major, B = XS [F_,D_] row-major (both K-contiguous).
// Tile 128(M)x256(N), BK=16, 256 threads, 8x16 micro-tile per thread.
// R2 was LDS-pipe bound (4x ds_read_b128 per 64 fmaf -> 67% VALU ceiling, measured 63%).
// 8x16 micro-tile: 6x ds_read_b128 per 128 fmaf -> 89% ceiling, 2x outputs per kk.
// Each C[m][n] remains ONE strictly-ascending-k fmaf chain: ip values bit-identical
// to the R2 kernel that passed (no argmax re-roll).
__global__ __launch_bounds__(256, 2) void gemm_argmax_kernel(
    const float* __restrict__ R, const float* __restrict__ XS,
    unsigned long long* __restrict__ amax)
{
    __shared__ float As[16][132];   // [k][m], 128+4 pad
    __shared__ float Bs[16][260];   // [k][n], 256+4 pad

    const int tid = threadIdx.x;
    const int bn = blockIdx.x;          // 0..127 (N tiles of 256)
    const int bm = blockIdx.y;          // 0..7   (M tiles of 128)
    const int m0 = bm * 128;
    const int n0 = bn * 256;

    // staging: A 128 rows x 16 k (2 float4/thread), B 256 rows x 16 k (4 float4/thread)
    const int arow = tid >> 1;          // 0..127
    const int aq   = tid & 1;           // which 8-float half of the 16 k
    const float* Aptr = R  + (size_t)(m0 + arow) * D_ + aq * 8;
    const float* Bptr = XS + (size_t)(n0 + tid) * D_;

    const int tx = tid & 15;            // n sub-tile (16 cols)
    const int ty = tid >> 4;            // m sub-tile (8 rows)

    float acc[8][16];
#pragma unroll
    for (int i = 0; i < 8; ++i)
#pragma unroll
        for (int j = 0; j < 16; ++j) acc[i][j] = 0.f;

    // prefetch first tiles
    float4 a0 = *(const float4*)(Aptr);
    float4 a1 = *(const float4*)(Aptr + 4);
    float4 b0 = *(const float4*)(Bptr);
    float4 b1 = *(const float4*)(Bptr + 4);
    float4 b2 = *(const float4*)(Bptr + 8);
    float4 b3 = *(const float4*)(Bptr + 12);

    for (int k0 = 0; k0 < D_; k0 += 16) {
        __syncthreads();   // previous compute done before overwriting LDS
        As[aq*8+0][arow] = a0.x; As[aq*8+1][arow] = a0.y;
        As[aq*8+2][arow] = a0.z; As[aq*8+3][arow] = a0.w;
        As[aq*8+4][arow] = a1.x; As[aq*8+5][arow] = a1.y;
        As[aq*8+6][arow] = a1.z; As[aq*8+7][arow] = a1.w;
        Bs[ 0][tid] = b0.x; Bs[ 1][tid] = b0.y; Bs[ 2][tid] = b0.z; Bs[ 3][tid] = b0.w;
        Bs[ 4][tid] = b1.x; Bs[ 5][tid] = b1.y; Bs[ 6][tid] = b1.z; Bs[ 7][tid] = b1.w;
        Bs[ 8][tid] = b2.x; Bs[ 9][tid] = b2.y; Bs[10][tid] = b2.z; Bs[11][tid] = b2.w;
        Bs[12][tid] = b3.x; Bs[13][tid] = b3.y; Bs[14][tid] = b3.z; Bs[15][tid] = b3.w;
        __syncthreads();
        if (k0 + 16 < D_) {   // prefetch next tiles during compute
            a0 = *(const float4*)(Aptr + k0 + 16);
            a1 = *(const float4*)(Aptr + k0 + 20);
            b0 = *(const float4*)(Bptr + k0 + 16);
            b1 = *(const float4*)(Bptr + k0 + 20);
            b2 = *(const float4*)(Bptr + k0 + 24);
            b3 = *(const float4*)(Bptr + k0 + 28);
        }
#pragma unroll
        for (int kk = 0; kk < 16; ++kk) {
            float4 av0 = *(const float4*)(&As[kk][ty*8]);
            float4 av1 = *(const float4*)(&As[kk][ty*8+4]);
            float4 bv0 = *(const float4*)(&Bs[kk][tx*16]);
            float4 bv1 = *(const float4*)(&Bs[kk][tx*16+4]);
            float4 bv2 = *(const float4*)(&Bs[kk][tx*16+8]);
            float4 bv3 = *(const float4*)(&Bs[kk][tx*16+12]);
            float a[8]  = {av0.x, av0.y, av0.z, av0.w, av1.x, av1.y, av1.z, av1.w};
            float bb[16] = {bv0.x, bv0.y, bv0.z, bv0.w, bv1.x, bv1.y, bv1.z, bv1.w,
                            bv2.x, bv2.y, bv2.z, bv2.w, bv3.x, bv3.y, bv3.z, bv3.w};
#pragma unroll
            for (int i = 0; i < 8; ++i)
#pragma unroll
                for (int j = 0; j < 16; ++j)
                    acc[i][j] = fmaf(a[i], bb[j], acc[i][j]);
        }
    }

    // ---- argmax epilogue: per-thread best over its 16 cols, then shfl_xor across the
    // 16 consecutive lanes (tx=0..15, fixed ty) that own this m-row; no LDS needed ----
#pragma unroll
    for (int i = 0; i < 8; ++i) {
        unsigned long long best = 0ull;
#pragma unroll
        for (int j = 0; j < 16; ++j) {
            unsigned long long key = packkey(acc[i][j], (unsigned int)(n0 + tx*16 + j));
            best = (key > best) ? key : best;
        }
        for (int off = 8; off > 0; off >>= 1) {
            unsigned long long o = __shfl_xor(best, off);
            best = (o > best) ? o : best;
        }
        if (tx == 0) atomicMax(&amax[m0 + ty*8 + i], best);
    }
}

// ----------------- per-row sparse update: select, grad, step, relu, residual -----------------
__global__ __launch_bounds__(256) void update_kernel(
    const float* __restrict__ X, const float* __restrict__ XS,
    float* __restrict__ Rres,
    int* __restrict__ a_idx, float* __restrict__ a_w, int* __restrict__ a_cnt,
    unsigned long long* __restrict__ amax)
{
    const int b = blockIdx.x;
    const int tid = threadIdx.x;
    __shared__ float s_r[D_];
    __shared__ int   s_idx[33];
    __shared__ float s_w[33];
    __shared__ float s_g[33];
    __shared__ int   s_cnt;
    __shared__ float s_red[8];

    for (int d = tid; d < D_; d += 256) s_r[d] = Rres[(size_t)b * D_ + d];

    if (tid == 0) {
        int cnt = a_cnt[b];
        for (int j = 0; j < cnt; ++j) { s_idx[j] = a_idx[b*KSLOTS + j]; s_w[j] = a_w[b*KSLOTS + j]; }
        unsigned long long key = amax[b];
        int ni = (int)(0xFFFFFFFFu - (unsigned int)(key & 0xFFFFFFFFull));
        bool found = false;
        for (int j = 0; j < cnt; ++j) found = found || (s_idx[j] == ni);
        if (!found) {  // insert keeping indices ascending (matches numpy's sum-over-f order)
            int p = cnt;
            while (p > 0 && s_idx[p-1] > ni) { s_idx[p] = s_idx[p-1]; s_w[p] = s_w[p-1]; --p; }
            s_idx[p] = ni; s_w[p] = 0.f; ++cnt;
        }
        s_cnt = cnt;
    }
    __syncthreads();
    const int cnt = s_cnt;
    const int wave = tid >> 6, lane = tid & 63;

    // grad_j = <r, xs[idx_j]> (one wave per atom, round-robin)
    for (int j = wave; j < cnt; j += 4) {
        const float* xr = XS + (size_t)s_idx[j] * D_;
        float sum = 0.f;
#pragma unroll
        for (int i = 0; i < D_/64; ++i) { int d = lane + (i << 6); sum = fmaf(s_r[d], xr[d], sum); }
        for (int off = 32; off > 0; off >>= 1) sum += __shfl_down(sum, off);
        if (lane == 0) s_g[j] = sum;
    }
    __syncthreads();

    // c = grad @ xs (active atoms, ascending index); reduce c.c and c.r
    float cs = 0.f, cr = 0.f;
#pragma unroll
    for (int v = 0; v < 4; ++v) {
        const int d = tid + (v << 8);
        float cv = 0.f;
        for (int j = 0; j < cnt; ++j) cv = fmaf(s_g[j], XS[(size_t)s_idx[j]*D_ + d], cv);
        cs = fmaf(cv, cv, cs);
        cr = fmaf(cv, s_r[d], cr);
    }
    for (int off = 32; off > 0; off >>= 1) { cs += __shfl_down(cs, off); cr += __shfl_down(cr, off); }
    if (lane == 0) { s_red[wave] = cs; s_red[4 + wave] = cr; }
    __syncthreads();

    if (tid == 0) {
        const float cs_t = s_red[0] + s_red[1] + s_red[2] + s_red[3];
        const float cr_t = s_red[4] + s_red[5] + s_red[6] + s_red[7];
        const float ss = cr_t / fmaxf(cs_t, 1e-3f);
        int nc = 0;
        for (int j = 0; j < cnt; ++j) {           // weights = relu(w + ss*grad), drop zeros
            float nw = s_w[j] + ss * s_g[j];
            if (nw > 0.f) { s_idx[nc] = s_idx[j]; s_w[nc] = nw; ++nc; }
        }
        s_cnt = nc;
        a_cnt[b] = nc;
        for (int j = 0; j < nc; ++j) { a_idx[b*KSLOTS + j] = s_idx[j]; a_w[b*KSLOTS + j] = s_w[j]; }
        amax[b] = 0ull;                            // reset for next step's GEMM
    }
    __syncthreads();
    const int nc = s_cnt;

    // fresh residual: r = x - sum_j w_j * xs[idx_j]  (ascending index, sum-then-subtract)
#pragma unroll
    for (int v = 0; v < 4; ++v) {
        const int d = tid + (v << 8);
        float s = 0.f;
        for (int j = 0; j < nc; ++j) s = fmaf(s_w[j], XS[(size_t)s_idx[j]*D_ + d], s);
        Rres[(size_t)b*D_ + d] = X[(size_t)b*D_ + d] - s;
    }
}

// ----------------- finalize: top_k, decode x/y, losses, write outputs -----------------
__global__ __launch_bounds__(256) void finalize_kernel(
    const float* __restrict__ Y,
    const float* __restrict__ XS, const float* __restrict__ YS,
    const int* __restrict__ a_idx, const float* __restrict__ a_w, const int* __restrict__ a_cnt,
    float* __restrict__ out)
{
    const int b = blockIdx.x, tid = threadIdx.x;
    __shared__ int   s_idx[KSLOTS];
    __shared__ float s_w[KSLOTS];
    __shared__ int   o_idx[KSLOTS];
    __shared__ float o_w[KSLOTS];
    __shared__ float s_red[4];

    if (tid == 0) {
        int cnt = a_cnt[b];
        for (int j = 0; j < cnt; ++j) { s_idx[j] = a_idx[b*KSLOTS + j]; s_w[j] = a_w[b*KSLOTS + j]; }
        // insertion sort: desc weight, ties -> ascending index (lax.top_k semantics)
        for (int i = 1; i < cnt; ++i) {
            int ii = s_idx[i]; float ww = s_w[i];
            int p = i - 1;
            while (p >= 0 && (s_w[p] < ww || (s_w[p] == ww && s_idx[p] > ii))) {
                s_w[p+1] = s_w[p]; s_idx[p+1] = s_idx[p]; --p;
            }
            s_w[p+1] = ww; s_idx[p+1] = ii;
        }
        for (int j = 0; j < cnt; ++j) { o_idx[j] = s_idx[j]; o_w[j] = s_w[j]; }
        // pad remaining slots with the smallest indices whose weight is zero
        int p = cnt, f = 0;
        while (p < KSLOTS) {
            bool member = false;
            for (int j = 0; j < cnt; ++j) member = member || (s_idx[j] == f);
            if (!member) { o_idx[p] = f; o_w[p] = 0.f; ++p; }
            ++f;
        }
    }
    __syncthreads();

    if (tid < KSLOTS) {
        out[(size_t)b*KSLOTS + tid] = o_w[tid];
        out[32768 + (size_t)b*KSLOTS + tid] = (float)o_idx[tid];   // harness reads fp32
    }

    float lsum = 0.f;
    for (int d = tid; d < D_; d += 256) {
        float xr = 0.f, yr = 0.f;
#pragma unroll
        for (int k = 0; k < KSLOTS; ++k) {
            const size_t off = (size_t)o_idx[k] * D_ + d;
            xr = fmaf(o_w[k], XS[off], xr);
            yr = fmaf(o_w[k], YS[off], yr);
        }
        out[65536 + (size_t)b*D_ + d] = xr;
        out[65536 + 1048576 + (size_t)b*D_ + d] = yr;
        const float e = yr - Y[(size_t)b*D_ + d];
        lsum = fmaf(e, e, lsum);
    }
    const int wave = tid >> 6, lane = tid & 63;
    for (int off = 32; off > 0; off >>= 1) lsum += __shfl_down(lsum, off);
    if (lane == 0) s_red[wave] = lsum;
    __syncthreads();
    if (tid == 0) out[65536 + 2097152 + b] = s_red[0] + s_red[1] + s_red[2] + s_red[3];
}

extern "C" void kernel_launch(void* const* d_in, const int* in_sizes, int n_in,
                              void* d_out, int out_size, void* d_ws, size_t ws_size,
                              hipStream_t stream) {
    (void)in_sizes; (void)n_in; (void)out_size; (void)ws_size;
    const float* x  = (const float*)d_in[0];
    const float* y  = (const float*)d_in[1];
    const float* xs = (const float*)d_in[2];
    const float* ys = (const float*)d_in[3];
    // d_in[4] = target_l0 (hardcoded 32; shapes are fixed)
    float* out = (float*)d_out;

    // workspace layout (~4.3 MB)
    char* ws = (char*)d_ws;
    float*              Rres  = (float*)(ws);                                   // 4 MB
    unsigned long long* amax  = (unsigned long long*)(ws + 4*1024*1024);        // 8 KB
    int*                a_cnt = (int*)(ws + 4*1024*1024 + 8192);                // 4 KB
    int*                a_idx = (int*)(ws + 4*1024*1024 + 8192 + 4096);         // 128 KB
    float*              a_w   = (float*)(ws + 4*1024*1024 + 8192 + 4096 + 131072); // 128 KB

    init_kernel<<<B_, 256, 0, stream>>>(x, Rres, a_cnt, amax);

    dim3 ggrid(F_/256, B_/128);   // (128, 8)
    for (int t = 0; t < T_; ++t) {
        gemm_argmax_kernel<<<ggrid, 256, 0, stream>>>(Rres, xs, amax);
        update_kernel<<<B_, 256, 0, stream>>>(x, xs, Rres, a_idx, a_w, a_cnt, amax);
    }
    finalize_kernel<<<B_, 256, 0, stream>>>(y, xs, ys, a_idx, a_w, a_cnt, out);
}